// Round 4
// baseline (225.944 us; speedup 1.0000x reference)
//
#include <hip/hip_runtime.h>

// ---------------------------------------------------------------------------
// SelfAttention: qkv = X@W + b ; per-head softmax(q k^T * sqrt(64)) @ v
// fp32 in/out. Precision: split-bf16 3-pass MFMA (hi/lo) for projection and
// Q*K^T, fp32 softmax (exp2 domain), bf16 PV.
// v4: attn -> 4 waves x 32 q-rows (halves per-row LDS K/V traffic), P stride
//     76, batched defer-max ballot, V-frag reuse across row-blocks.
// ---------------------------------------------------------------------------

#define S_LEN 2048
#define NH    16
#define DH    64
#define DM    1024
#define EW    3072   // NH*(64+64+64)
#define NROWS 4096   // B*S
#define NT    32     // KV tiles of 64 keys
#define PSTR  76     // P LDS row stride (shorts)

// 8 * log2(e): folds the sqrt(64) score scale AND the exp->exp2 conversion
#define QSCALE 11.5415603f

using f32x4 = __attribute__((ext_vector_type(4))) float;
using bf8   = __attribute__((ext_vector_type(8))) short;   // 8 bf16 (4 VGPRs)
using s4v   = __attribute__((ext_vector_type(4))) short;

static __device__ __forceinline__ short f2bf(float f) {
  union { float f; unsigned u; } a; a.f = f;
  unsigned r = a.u + 0x7fffu + ((a.u >> 16) & 1u);   // RNE
  return (short)(r >> 16);
}
static __device__ __forceinline__ float bf2f(short h) {
  union { float f; unsigned u; } a;
  a.u = ((unsigned)(unsigned short)h) << 16;
  return a.f;
}
static __device__ __forceinline__ short f2bf_trunc(float f) {
  union { float f; unsigned u; } a; a.f = f;
  return (short)(a.u >> 16);
}
static __device__ __forceinline__ void gl16(const void* g, void* l) {
  __builtin_amdgcn_global_load_lds(
      (const __attribute__((address_space(1))) void*)g,
      (__attribute__((address_space(3))) void*)l, 16, 0, 0);
}

// --------------------------- prep: split X into bf16 hi/lo ------------------
__global__ __launch_bounds__(256) void prep_x(const float* __restrict__ X,
                                              short* __restrict__ Xh,
                                              short* __restrict__ Xl) {
  int i = blockIdx.x * 256 + threadIdx.x;              // 1,048,576 float4s
  float4 v = ((const float4*)X)[i];
  s4v h, l;
  h.x = f2bf(v.x); l.x = f2bf(v.x - bf2f(h.x));
  h.y = f2bf(v.y); l.y = f2bf(v.y - bf2f(h.y));
  h.z = f2bf(v.z); l.z = f2bf(v.z - bf2f(h.z));
  h.w = f2bf(v.w); l.w = f2bf(v.w - bf2f(h.w));
  ((s4v*)Xh)[i] = h;
  ((s4v*)Xl)[i] = l;
}

// ------------------- prep: transpose W -> W^T, split hi/lo ------------------
__global__ __launch_bounds__(256) void prep_w(const float* __restrict__ W,
                                              short* __restrict__ Wth,
                                              short* __restrict__ Wtl) {
  __shared__ float t[32][33];
  int n0 = blockIdx.x * 32;
  int k0 = blockIdx.y * 32;
  int tx = threadIdx.x & 31;
  int ty = threadIdx.x >> 5;        // 0..7
#pragma unroll
  for (int i = 0; i < 32; i += 8)
    t[ty + i][tx] = W[(size_t)(k0 + ty + i) * EW + n0 + tx];
  __syncthreads();
#pragma unroll
  for (int i = 0; i < 32; i += 8) {
    float v = t[tx][ty + i];        // k = k0+tx, n = n0+ty+i
    short hi = f2bf(v);
    short lo = f2bf(v - bf2f(hi));
    size_t o = (size_t)(n0 + ty + i) * DM + k0 + tx;
    Wth[o] = hi; Wtl[o] = lo;
  }
}

// --------------------------- projection GEMM --------------------------------
// C(4096x3072) = X(4096x1024) @ W ; 128x128 tile, 4 waves, BK=32, 3-pass MFMA.
// Staging via global_load_lds (16B), linear LDS dest + pre-swizzled global
// source chunk (^= (row>>1)&3), same XOR on the ds_read side (rule #21).
__global__ __launch_bounds__(256) void proj(
    const short* __restrict__ Xh, const short* __restrict__ Xl,
    const short* __restrict__ Wth, const short* __restrict__ Wtl,
    const float* __restrict__ bias,
    short* __restrict__ Qh, short* __restrict__ Ql,
    short* __restrict__ Kh, short* __restrict__ Kl,
    short* __restrict__ Vt) {
  __shared__ short Ah[4096], Al[4096], Bh[4096], Bl[4096];   // 8KB each, 32KB
  const int tid = threadIdx.x;
  const int lane = tid & 63, w = tid >> 6;
  const int wr = w >> 1, wc = w & 1;
  const int c = lane & 15, g = lane >> 4;

  // XCD-contiguous remap: 96 consecutive logical blocks (3 B-tiles) per XCD
  const int id = blockIdx.x;                  // 0..767
  const int lid = (id & 7) * 96 + (id >> 3);
  const int rowBase = (lid & 31) * 128;
  const int colBase = (lid >> 5) * 128;

  f32x4 acc[4][4] = {};

  const int sr  = 32 * w + (lane >> 2);
  const int csw = ((lane & 3) ^ ((lane >> 3) & 3)) * 8;   // shorts
  const int ldsw = w * 1024;                              // shorts, seg base
  const size_t aBase = (size_t)(rowBase + sr) * DM + csw;
  const size_t bBase = (size_t)(colBase + sr) * DM + csw;

  // read-side swizzle: row = (16-aligned) + c  ->  f(row) = (c>>1)&3
  const int rsw = (g ^ ((c >> 1) & 3)) * 8;

  for (int kt = 0; kt < DM; kt += 32) {
    gl16(&Xh[aBase + kt],            &Ah[ldsw]);
    gl16(&Xh[aBase + kt + 16 * DM],  &Ah[ldsw + 512]);
    gl16(&Xl[aBase + kt],            &Al[ldsw]);
    gl16(&Xl[aBase + kt + 16 * DM],  &Al[ldsw + 512]);
    gl16(&Wth[bBase + kt],           &Bh[ldsw]);
    gl16(&Wth[bBase + kt + 16 * DM], &Bh[ldsw + 512]);
    gl16(&Wtl[bBase + kt],           &Bl[ldsw]);
    gl16(&Wtl[bBase + kt + 16 * DM], &Bl[ldsw + 512]);
    __syncthreads();                 // drains vmcnt: tile visible

    bf8 ah[4], al4[4], bh[4], bl[4];
#pragma unroll
    for (int m = 0; m < 4; ++m) {
      int ro = (wr * 64 + m * 16 + c) * 32 + rsw;
      ah[m]  = *(const bf8*)&Ah[ro];
      al4[m] = *(const bf8*)&Al[ro];
    }
#pragma unroll
    for (int n = 0; n < 4; ++n) {
      int ro = (wc * 64 + n * 16 + c) * 32 + rsw;
      bh[n] = *(const bf8*)&Bh[ro];
      bl[n] = *(const bf8*)&Bl[ro];
    }
    __builtin_amdgcn_s_setprio(1);
#pragma unroll
    for (int m = 0; m < 4; ++m)
#pragma unroll
      for (int n = 0; n < 4; ++n) {
        acc[m][n] = __builtin_amdgcn_mfma_f32_16x16x32_bf16(al4[m], bh[n], acc[m][n], 0, 0, 0);
        acc[m][n] = __builtin_amdgcn_mfma_f32_16x16x32_bf16(ah[m], bl[n], acc[m][n], 0, 0, 0);
        acc[m][n] = __builtin_amdgcn_mfma_f32_16x16x32_bf16(ah[m], bh[n], acc[m][n], 0, 0, 0);
      }
    __builtin_amdgcn_s_setprio(0);
    __syncthreads();                 // all reads done before next staging
  }

  // epilogue: bias + scatter to per-head Q/K/V layouts
#pragma unroll
  for (int m = 0; m < 4; ++m)
#pragma unroll
    for (int n = 0; n < 4; ++n)
#pragma unroll
      for (int j = 0; j < 4; ++j) {
        int grow = rowBase + wr * 64 + m * 16 + g * 4 + j;   // 0..4095
        int gcol = colBase + wc * 64 + n * 16 + c;           // 0..3071
        float v = acc[m][n][j] + bias[gcol];
        int bb = grow >> 11, s = grow & 2047;
        int h = gcol / 192, e = gcol - h * 192;
        size_t hb = (size_t)(bb * NH + h);
        if (e < DH) {                      // Q: fold in 8*log2e (exp2 domain)
          float q8 = v * QSCALE;
          short hi = f2bf(q8);
          short lo = f2bf(q8 - bf2f(hi));
          size_t idx = (hb * S_LEN + s) * DH + e;
          Qh[idx] = hi; Ql[idx] = lo;
        } else if (e < 2 * DH) {           // K: [bh][tile][row(key)][d]
          short hi = f2bf(v);
          short lo = f2bf(v - bf2f(hi));
          int tile = s >> 6, row = s & 63;
          size_t idx = ((hb * NT + tile) * (size_t)4096) + row * 64 + (e - DH);
          Kh[idx] = hi; Kl[idx] = lo;
        } else {                           // V: [bh][tile][d][key]
          int tile = s >> 6, key = s & 63;
          size_t idx = ((hb * NT + tile) * (size_t)4096) + (e - 2 * DH) * 64 + key;
          Vt[idx] = f2bf(v);
        }
      }
}

// ------------------------------ attention -----------------------------------
// 512 blocks (XCD-swizzled), 4 waves x 32 q-rows share one bh; KV tiles
// double-buffered in LDS, reg-staged prefetch, ONE barrier per tile;
// exp2-domain online softmax, batched defer-max, per-lane lsum partials.
__global__ __launch_bounds__(256, 2) void attn(
    const short* __restrict__ Qh, const short* __restrict__ Ql,
    const short* __restrict__ KhG, const short* __restrict__ KlG,
    const short* __restrict__ VtG, float* __restrict__ out) {
  __shared__ short KHs[2][4096];   // 16 KB
  __shared__ short KLs[2][4096];   // 16 KB
  __shared__ short Vs[2][4096];    // 16 KB
  __shared__ short P[4][32 * PSTR];  // 19 KB, per-wave private P staging

  const int tid = threadIdx.x;
  const int lane = tid & 63, w = tid >> 6;   // w = 0..3
  const int c = lane & 15, g = lane >> 4;
  const int id = blockIdx.x;                   // 0..511
  const int lid = (id & 7) * 64 + (id >> 3);   // 64 consecutive per XCD
  const int bh = lid >> 4;
  const int q0 = (lid & 15) * 128 + w * 32;
  const size_t qBase  = (size_t)bh * S_LEN * DH;
  const size_t kvBase = (size_t)bh * NT * 4096;

  // staging geometry: wave w stages rows [w*16, w*16+16); each lane one 32B
  // (2x16B) segment; LDS slots XOR-swizzled by row&7 (both chunks).
  const int srow  = w * 16 + (lane >> 2);
  const int sslot = 2 * (lane & 3);
  const int sf    = srow & 7;
  const int sgo   = srow * 64 + sslot * 8;            // global shorts in tile
  const int sd0   = srow * 64 + ((sslot ^ sf)) * 8;   // LDS dests
  const int sd1   = srow * 64 + (((sslot + 1) ^ sf)) * 8;

  // q fragments (hi/lo) for 2 row-blocks
  bf8 qh[2][2], ql[2][2];
#pragma unroll
  for (int rb = 0; rb < 2; ++rb)
#pragma unroll
    for (int kc = 0; kc < 2; ++kc) {
      size_t idx = qBase + (size_t)(q0 + rb * 16 + c) * DH + kc * 32 + g * 8;
      qh[rb][kc] = *(const bf8*)&Qh[idx];
      ql[rb][kc] = *(const bf8*)&Ql[idx];
    }

  // t-invariant swizzled fragment offsets (row&7 == c&7)
  int koff[2][4];
#pragma unroll
  for (int kc = 0; kc < 2; ++kc)
#pragma unroll
    for (int i = 0; i < 4; ++i)
      koff[kc][i] = (i * 16 + c) * 64 + (((kc * 4 + g) ^ (c & 7)) << 3);

  float mrun[8], lpart[8];
#pragma unroll
  for (int j = 0; j < 8; ++j) { mrun[j] = -INFINITY; lpart[j] = 0.f; }
  f32x4 o[2][4] = {};
  short* myP = &P[w][0];

  // prologue: stage tile 0
  {
    bf8 a0 = *(const bf8*)&KhG[kvBase + sgo];
    bf8 a1 = *(const bf8*)&KhG[kvBase + sgo + 8];
    bf8 b0 = *(const bf8*)&KlG[kvBase + sgo];
    bf8 b1 = *(const bf8*)&KlG[kvBase + sgo + 8];
    bf8 d0 = *(const bf8*)&VtG[kvBase + sgo];
    bf8 d1 = *(const bf8*)&VtG[kvBase + sgo + 8];
    *(bf8*)&KHs[0][sd0] = a0; *(bf8*)&KHs[0][sd1] = a1;
    *(bf8*)&KLs[0][sd0] = b0; *(bf8*)&KLs[0][sd1] = b1;
    *(bf8*)&Vs[0][sd0]  = d0; *(bf8*)&Vs[0][sd1]  = d1;
  }
  __syncthreads();

  for (int t = 0; t < NT; ++t) {
    const int cur = t & 1, nxt = cur ^ 1;
    bf8 rkh0, rkh1, rkl0, rkl1, rv0, rv1;
    if (t + 1 < NT) {                       // issue early; completes under compute
      size_t tb = kvBase + (size_t)(t + 1) * 4096 + sgo;
      rkh0 = *(const bf8*)&KhG[tb];     rkh1 = *(const bf8*)&KhG[tb + 8];
      rkl0 = *(const bf8*)&KlG[tb];     rkl1 = *(const bf8*)&KlG[tb + 8];
      rv0  = *(const bf8*)&VtG[tb];     rv1  = *(const bf8*)&VtG[tb + 8];
    }
    const short* KH = &KHs[cur][0];
    const short* KL = &KLs[cur][0];
    const short* VV = &Vs[cur][0];
    // scores: 3-pass split-bf16 (log2 domain)
    f32x4 sc[2][4];
#pragma unroll
    for (int rb = 0; rb < 2; ++rb)
#pragma unroll
      for (int nb = 0; nb < 4; ++nb) sc[rb][nb] = f32x4{0.f, 0.f, 0.f, 0.f};
    __builtin_amdgcn_s_setprio(1);
#pragma unroll
    for (int nb = 0; nb < 4; ++nb)
#pragma unroll
      for (int kc = 0; kc < 2; ++kc) {
        bf8 kh = *(const bf8*)&KH[koff[kc][nb]];
        bf8 kl = *(const bf8*)&KL[koff[kc][nb]];
#pragma unroll
        for (int rb = 0; rb < 2; ++rb) {
          sc[rb][nb] = __builtin_amdgcn_mfma_f32_16x16x32_bf16(ql[rb][kc], kh, sc[rb][nb], 0, 0, 0);
          sc[rb][nb] = __builtin_amdgcn_mfma_f32_16x16x32_bf16(qh[rb][kc], kl, sc[rb][nb], 0, 0, 0);
          sc[rb][nb] = __builtin_amdgcn_mfma_f32_16x16x32_bf16(qh[rb][kc], kh, sc[rb][nb], 0, 0, 0);
        }
      }
    __builtin_amdgcn_s_setprio(0);
    // row maxima (16-lane tree per row)
    float t0[8];
#pragma unroll
    for (int rb = 0; rb < 2; ++rb)
#pragma unroll
      for (int j = 0; j < 4; ++j) {
        float m0 = fmaxf(fmaxf(sc[rb][0][j], sc[rb][1][j]),
                         fmaxf(sc[rb][2][j], sc[rb][3][j]));
        m0 = fmaxf(m0, __shfl_xor(m0, 1));
        m0 = fmaxf(m0, __shfl_xor(m0, 2));
        m0 = fmaxf(m0, __shfl_xor(m0, 4));
        m0 = fmaxf(m0, __shfl_xor(m0, 8));
        t0[rb * 4 + j] = m0;
      }
    // batched defer-max: one ballot for all 8 rows
    float need = t0[0] - mrun[0];
#pragma unroll
    for (int j = 1; j < 8; ++j) need = fmaxf(need, t0[j] - mrun[j]);
    if (__any(need > 8.0f)) {
#pragma unroll
      for (int rb = 0; rb < 2; ++rb)
#pragma unroll
        for (int j = 0; j < 4; ++j) {
          int r = rb * 4 + j;
          float mnew = fmaxf(mrun[r], t0[r]);
          float scale = exp2f(mrun[r] - mnew);
          mrun[r] = mnew;
          lpart[r] *= scale;
          o[rb][0][j] *= scale; o[rb][1][j] *= scale;
          o[rb][2][j] *= scale; o[rb][3][j] *= scale;
        }
    }
    // P = exp2(s - m), bf16-trunc to LDS; per-lane lsum partials
#pragma unroll
    for (int rb = 0; rb < 2; ++rb)
#pragma unroll
      for (int j = 0; j < 4; ++j) {
        float m = mrun[rb * 4 + j];
        float p0 = exp2f(sc[rb][0][j] - m), p1 = exp2f(sc[rb][1][j] - m);
        float p2 = exp2f(sc[rb][2][j] - m), p3 = exp2f(sc[rb][3][j] - m);
        lpart[rb * 4 + j] += (p0 + p1) + (p2 + p3);
        int pr = (rb * 16 + g * 4 + j) * PSTR + c;
        myP[pr]      = f2bf_trunc(p0);
        myP[pr + 16] = f2bf_trunc(p1);
        myP[pr + 32] = f2bf_trunc(p2);
        myP[pr + 48] = f2bf_trunc(p3);
      }
    // PV: P rows from wave-private LDS; V fragments reused across row-blocks
    __builtin_amdgcn_s_setprio(1);
#pragma unroll
    for (int kc = 0; kc < 2; ++kc) {
      bf8 pa0 = *(const bf8*)&myP[(c)      * PSTR + kc * 32 + g * 8];
      bf8 pa1 = *(const bf8*)&myP[(16 + c) * PSTR + kc * 32 + g * 8];
#pragma unroll
      for (int db = 0; db < 4; ++db) {
        bf8 vb = *(const bf8*)&VV[koff[kc][db]];
        o[0][db] = __builtin_amdgcn_mfma_f32_16x16x32_bf16(pa0, vb, o[0][db], 0, 0, 0);
        o[1][db] = __builtin_amdgcn_mfma_f32_16x16x32_bf16(pa1, vb, o[1][db], 0, 0, 0);
      }
    }
    __builtin_amdgcn_s_setprio(0);
    // write prefetched tile into nxt (readers only touch cur) — ONE barrier
    if (t + 1 < NT) {
      *(bf8*)&KHs[nxt][sd0] = rkh0; *(bf8*)&KHs[nxt][sd1] = rkh1;
      *(bf8*)&KLs[nxt][sd0] = rkl0; *(bf8*)&KLs[nxt][sd1] = rkl1;
      *(bf8*)&Vs[nxt][sd0]  = rv0;  *(bf8*)&Vs[nxt][sd1]  = rv1;
    }
    __syncthreads();
  }

  float lsum[8];
#pragma unroll
  for (int j = 0; j < 8; ++j) {
    float s = lpart[j];
    s += __shfl_xor(s, 1);
    s += __shfl_xor(s, 2);
    s += __shfl_xor(s, 4);
    s += __shfl_xor(s, 8);
    lsum[j] = s;
  }
  const int b = bh >> 4, h = bh & 15;
#pragma unroll
  for (int rb = 0; rb < 2; ++rb)
#pragma unroll
    for (int db = 0; db < 4; ++db)
#pragma unroll
      for (int j = 0; j < 4; ++j) {
        int s = q0 + rb * 16 + g * 4 + j;
        out[((size_t)b * S_LEN + s) * DM + h * DH + db * 16 + c] =
            o[rb][db][j] / lsum[rb * 4 + j];
      }
}

// ---------------------------------------------------------------------------
extern "C" void kernel_launch(void* const* d_in, const int* in_sizes, int n_in,
                              void* d_out, int out_size, void* d_ws, size_t ws_size,
                              hipStream_t stream) {
  const float* X    = (const float*)d_in[0];
  const float* W    = (const float*)d_in[1];
  const float* bias = (const float*)d_in[2];
  float* out = (float*)d_out;

  char* ws = (char*)d_ws;
  size_t off = 0;
  auto take = [&](size_t bytes) {
    void* p = ws + off;
    off += (bytes + 255) & ~(size_t)255;
    return p;
  };
  short* Xh  = (short*)take((size_t)NROWS * DM * 2);   // 8.4 MB
  short* Xl  = (short*)take((size_t)NROWS * DM * 2);
  short* Wth = (short*)take((size_t)EW * DM * 2);      // 6.3 MB
  short* Wtl = (short*)take((size_t)EW * DM * 2);
  short* Qh  = (short*)take((size_t)2 * NH * S_LEN * DH * 2);  // 8.4 MB each
  short* Ql  = (short*)take((size_t)2 * NH * S_LEN * DH * 2);
  short* Kh  = (short*)take((size_t)2 * NH * NT * 4096 * 2);
  short* Kl  = (short*)take((size_t)2 * NH * NT * 4096 * 2);
  short* Vt  = (short*)take((size_t)2 * NH * NT * 4096 * 2);
  // total ~71.3 MB of workspace

  prep_x<<<dim3(4096), dim3(256), 0, stream>>>(X, Xh, Xl);
  prep_w<<<dim3(EW / 32, DM / 32), dim3(256), 0, stream>>>(W, Wth, Wtl);
  proj<<<dim3(768), dim3(256), 0, stream>>>(
      Xh, Xl, Wth, Wtl, bias, Qh, Ql, Kh, Kl, Vt);
  attn<<<dim3(512), dim3(256), 0, stream>>>(
      Qh, Ql, Kh, Kl, Vt, out);
}

// Round 5
// 206.650 us; speedup vs baseline: 1.0934x; 1.0934x over previous
//
#include <hip/hip_runtime.h>

// ---------------------------------------------------------------------------
// SelfAttention: qkv = X@W + b ; per-head softmax(q k^T * sqrt(64)) @ v
// fp32 in/out. Precision: split-bf16 3-pass MFMA (hi/lo) for projection and
// Q*K^T, fp32 softmax (exp2 domain), bf16 PV.
// v5: attn -> swapped QK^T (S = mfma(K,Q)) so each lane owns one q-row's
//     scores: in-lane softmax (2 shfl/tile), P stays in registers (permuted
//     V storage makes lane-local p's exactly the PV A-fragment), KV staged
//     via global_load_lds from pre-swizzled ws layouts (written by proj).
// ---------------------------------------------------------------------------

#define S_LEN 2048
#define NH    16
#define DH    64
#define DM    1024
#define EW    3072   // NH*(64+64+64)
#define NROWS 4096   // B*S
#define NT    32     // KV tiles of 64 keys

// 8 * log2(e): folds the sqrt(64) score scale AND the exp->exp2 conversion
#define QSCALE 11.5415603f

using f32x4 = __attribute__((ext_vector_type(4))) float;
using bf8   = __attribute__((ext_vector_type(8))) short;   // 8 bf16 (4 VGPRs)
using s4v   = __attribute__((ext_vector_type(4))) short;

static __device__ __forceinline__ short f2bf(float f) {
  union { float f; unsigned u; } a; a.f = f;
  unsigned r = a.u + 0x7fffu + ((a.u >> 16) & 1u);   // RNE
  return (short)(r >> 16);
}
static __device__ __forceinline__ float bf2f(short h) {
  union { float f; unsigned u; } a;
  a.u = ((unsigned)(unsigned short)h) << 16;
  return a.f;
}
static __device__ __forceinline__ unsigned fbits(float f) {
  union { float f; unsigned u; } a; a.f = f; return a.u;
}
static __device__ __forceinline__ void gl16(const void* g, void* l) {
  __builtin_amdgcn_global_load_lds(
      (const __attribute__((address_space(1))) void*)g,
      (__attribute__((address_space(3))) void*)l, 16, 0, 0);
}

// --------------------------- prep: split X into bf16 hi/lo ------------------
__global__ __launch_bounds__(256) void prep_x(const float* __restrict__ X,
                                              short* __restrict__ Xh,
                                              short* __restrict__ Xl) {
  int i = blockIdx.x * 256 + threadIdx.x;              // 1,048,576 float4s
  float4 v = ((const float4*)X)[i];
  s4v h, l;
  h.x = f2bf(v.x); l.x = f2bf(v.x - bf2f(h.x));
  h.y = f2bf(v.y); l.y = f2bf(v.y - bf2f(h.y));
  h.z = f2bf(v.z); l.z = f2bf(v.z - bf2f(h.z));
  h.w = f2bf(v.w); l.w = f2bf(v.w - bf2f(h.w));
  ((s4v*)Xh)[i] = h;
  ((s4v*)Xl)[i] = l;
}

// ------------------- prep: transpose W -> W^T, split hi/lo ------------------
__global__ __launch_bounds__(256) void prep_w(const float* __restrict__ W,
                                              short* __restrict__ Wth,
                                              short* __restrict__ Wtl) {
  __shared__ float t[32][33];
  int n0 = blockIdx.x * 32;
  int k0 = blockIdx.y * 32;
  int tx = threadIdx.x & 31;
  int ty = threadIdx.x >> 5;        // 0..7
#pragma unroll
  for (int i = 0; i < 32; i += 8)
    t[ty + i][tx] = W[(size_t)(k0 + ty + i) * EW + n0 + tx];
  __syncthreads();
#pragma unroll
  for (int i = 0; i < 32; i += 8) {
    float v = t[tx][ty + i];        // k = k0+tx, n = n0+ty+i
    short hi = f2bf(v);
    short lo = f2bf(v - bf2f(hi));
    size_t o = (size_t)(n0 + ty + i) * DM + k0 + tx;
    Wth[o] = hi; Wtl[o] = lo;
  }
}

// --------------------------- projection GEMM --------------------------------
// C(4096x3072) = X(4096x1024) @ W ; 128x128 tile, 4 waves, BK=32, 3-pass MFMA.
// Staging via global_load_lds (16B), linear LDS dest + pre-swizzled global
// source chunk, same XOR on the ds_read side (rule #21).
// Epilogue writes K/V in the attn kernel's pre-swizzled tile layouts.
__global__ __launch_bounds__(256) void proj(
    const short* __restrict__ Xh, const short* __restrict__ Xl,
    const short* __restrict__ Wth, const short* __restrict__ Wtl,
    const float* __restrict__ bias,
    short* __restrict__ Qh, short* __restrict__ Ql,
    short* __restrict__ Kh, short* __restrict__ Kl,
    short* __restrict__ Vt) {
  __shared__ short Ah[4096], Al[4096], Bh[4096], Bl[4096];   // 8KB each, 32KB
  const int tid = threadIdx.x;
  const int lane = tid & 63, w = tid >> 6;
  const int wr = w >> 1, wc = w & 1;
  const int c = lane & 15, g = lane >> 4;

  // XCD-contiguous remap: 96 consecutive logical blocks (3 B-tiles) per XCD
  const int id = blockIdx.x;                  // 0..767
  const int lid = (id & 7) * 96 + (id >> 3);
  const int rowBase = (lid & 31) * 128;
  const int colBase = (lid >> 5) * 128;

  f32x4 acc[4][4] = {};

  const int sr  = 32 * w + (lane >> 2);
  const int csw = ((lane & 3) ^ ((lane >> 3) & 3)) * 8;   // shorts
  const int ldsw = w * 1024;                              // shorts, seg base
  const size_t aBase = (size_t)(rowBase + sr) * DM + csw;
  const size_t bBase = (size_t)(colBase + sr) * DM + csw;

  // read-side swizzle: row = (16-aligned) + c  ->  f(row) = (c>>1)&3
  const int rsw = (g ^ ((c >> 1) & 3)) * 8;

  for (int kt = 0; kt < DM; kt += 32) {
    gl16(&Xh[aBase + kt],            &Ah[ldsw]);
    gl16(&Xh[aBase + kt + 16 * DM],  &Ah[ldsw + 512]);
    gl16(&Xl[aBase + kt],            &Al[ldsw]);
    gl16(&Xl[aBase + kt + 16 * DM],  &Al[ldsw + 512]);
    gl16(&Wth[bBase + kt],           &Bh[ldsw]);
    gl16(&Wth[bBase + kt + 16 * DM], &Bh[ldsw + 512]);
    gl16(&Wtl[bBase + kt],           &Bl[ldsw]);
    gl16(&Wtl[bBase + kt + 16 * DM], &Bl[ldsw + 512]);
    __syncthreads();                 // drains vmcnt: tile visible

    bf8 ah[4], al4[4], bh[4], bl[4];
#pragma unroll
    for (int m = 0; m < 4; ++m) {
      int ro = (wr * 64 + m * 16 + c) * 32 + rsw;
      ah[m]  = *(const bf8*)&Ah[ro];
      al4[m] = *(const bf8*)&Al[ro];
    }
#pragma unroll
    for (int n = 0; n < 4; ++n) {
      int ro = (wc * 64 + n * 16 + c) * 32 + rsw;
      bh[n] = *(const bf8*)&Bh[ro];
      bl[n] = *(const bf8*)&Bl[ro];
    }
    __builtin_amdgcn_s_setprio(1);
#pragma unroll
    for (int m = 0; m < 4; ++m)
#pragma unroll
      for (int n = 0; n < 4; ++n) {
        acc[m][n] = __builtin_amdgcn_mfma_f32_16x16x32_bf16(al4[m], bh[n], acc[m][n], 0, 0, 0);
        acc[m][n] = __builtin_amdgcn_mfma_f32_16x16x32_bf16(ah[m], bl[n], acc[m][n], 0, 0, 0);
        acc[m][n] = __builtin_amdgcn_mfma_f32_16x16x32_bf16(ah[m], bh[n], acc[m][n], 0, 0, 0);
      }
    __builtin_amdgcn_s_setprio(0);
    __syncthreads();                 // all reads done before next staging
  }

  // epilogue: bias + scatter to per-head Q/K/V layouts
#pragma unroll
  for (int m = 0; m < 4; ++m)
#pragma unroll
    for (int n = 0; n < 4; ++n)
#pragma unroll
      for (int j = 0; j < 4; ++j) {
        int grow = rowBase + wr * 64 + m * 16 + g * 4 + j;   // 0..4095
        int gcol = colBase + wc * 64 + n * 16 + c;           // 0..3071
        float v = acc[m][n][j] + bias[gcol];
        int bb = grow >> 11, s = grow & 2047;
        int h = gcol / 192, e = gcol - h * 192;
        size_t hb = (size_t)(bb * NH + h);
        if (e < DH) {                      // Q: fold in 8*log2e (exp2 domain)
          float q8 = v * QSCALE;
          short hi = f2bf(q8);
          short lo = f2bf(q8 - bf2f(hi));
          size_t idx = (hb * S_LEN + s) * DH + e;
          Qh[idx] = hi; Ql[idx] = lo;
        } else if (e < 2 * DH) {
          // K: [bh][tile][key][d], chunk-XOR-swizzled: chunk ^= key&7
          short hi = f2bf(v);
          short lo = f2bf(v - bf2f(hi));
          int tile = s >> 6, r = s & 63, d = e - DH;
          size_t idx = ((hb * NT + tile) * (size_t)4096) + r * 64 +
                       ((((d >> 3) ^ (r & 7)) << 3) | (d & 7));
          Kh[idx] = hi; Kl[idx] = lo;
        } else {
          // V: [bh][tile][d][key-permuted], chunk-XOR-swizzled by d&7.
          // Within a d-row, key -> slot: kc=key>>5, g4=(key>>2)&3,
          // i = ((key>>4)&1)*4 + (key&3); slot = kc*32 + g4*8 + i.
          int tile = s >> 6, key = s & 63, d = e - 2 * DH;
          int kc = key >> 5, g4 = (key >> 2) & 3;
          int ii = (((key >> 4) & 1) << 2) | (key & 3);
          size_t idx = ((hb * NT + tile) * (size_t)4096) + d * 64 +
                       (((((kc << 2) | g4) ^ (d & 7)) << 3) | ii);
          Vt[idx] = f2bf(v);
        }
      }
}

// ------------------------------ attention -----------------------------------
// 512 blocks (XCD-swizzled), 8 waves x 16 q-rows share one bh. Swapped QK^T:
// sc = mfma(K,Q) puts one q-row's scores in each lane -> in-lane softmax,
// P packed in registers straight into the PV A-fragment (V key-permuted).
// KV staged via global_load_lds, double-buffered, ONE barrier per tile.
__global__ __launch_bounds__(512, 4) void attn(
    const short* __restrict__ Qh, const short* __restrict__ Ql,
    const short* __restrict__ KhG, const short* __restrict__ KlG,
    const short* __restrict__ VtG, float* __restrict__ out) {
  __shared__ short KHs[2][4096];   // 16 KB
  __shared__ short KLs[2][4096];   // 16 KB
  __shared__ short Vs[2][4096];    // 16 KB

  const int tid = threadIdx.x;
  const int lane = tid & 63, w = tid >> 6;     // 8 waves
  const int c = lane & 15, g = lane >> 4;
  const int id = blockIdx.x;                   // 0..511
  const int lid = (id & 7) * 64 + (id >> 3);   // 64 consecutive per XCD
  const int bh = lid >> 4;
  const int q0 = (lid & 15) * 128 + w * 16;
  const size_t qBase  = (size_t)bh * S_LEN * DH;
  const size_t kvBase = (size_t)bh * NT * 4096;

  const int seg = tid * 8;     // one 16B chunk per thread per buffer

  // q fragments (hi/lo), rows q0+c — used as the MFMA B operand
  bf8 qh[2], ql[2];
#pragma unroll
  for (int kc = 0; kc < 2; ++kc) {
    size_t idx = qBase + (size_t)(q0 + c) * DH + kc * 32 + g * 8;
    qh[kc] = *(const bf8*)&Qh[idx];
    ql[kc] = *(const bf8*)&Ql[idx];
  }

  // t-invariant swizzled fragment offsets ((i*16+c)&7 == c&7)
  int koff[2][4];
#pragma unroll
  for (int kc = 0; kc < 2; ++kc)
#pragma unroll
    for (int i = 0; i < 4; ++i)
      koff[kc][i] = (i * 16 + c) * 64 + (((kc * 4 + g) ^ (c & 7)) << 3);

  float mrun = -INFINITY, lpart = 0.f;   // state for q-row c (dup across g)
  f32x4 o[4] = {};                       // o[db][j]: row 4g+j, d = db*16+c

  // prologue: stage tile 0
  gl16(&KhG[kvBase + seg], &KHs[0][seg]);
  gl16(&KlG[kvBase + seg], &KLs[0][seg]);
  gl16(&VtG[kvBase + seg], &Vs[0][seg]);
  __syncthreads();

  for (int t = 0; t < NT; ++t) {
    const int cur = t & 1, nxt = cur ^ 1;
    if (t + 1 < NT) {                    // DMA next tile; lands under compute
      size_t tb = kvBase + (size_t)(t + 1) * 4096 + seg;
      gl16(&KhG[tb], &KHs[nxt][seg]);
      gl16(&KlG[tb], &KLs[nxt][seg]);
      gl16(&VtG[tb], &Vs[nxt][seg]);
    }
    const short* KH = &KHs[cur][0];
    const short* KL = &KLs[cur][0];
    const short* VV = &Vs[cur][0];

    // scores, swapped: sc[nb][j] = S[key=16nb+4g+j][q-row c]
    f32x4 sc[4];
    __builtin_amdgcn_s_setprio(1);
#pragma unroll
    for (int nb = 0; nb < 4; ++nb) {
      f32x4 s = {};
#pragma unroll
      for (int kc = 0; kc < 2; ++kc) {
        bf8 kh = *(const bf8*)&KH[koff[kc][nb]];
        bf8 kl = *(const bf8*)&KL[koff[kc][nb]];
        s = __builtin_amdgcn_mfma_f32_16x16x32_bf16(kh, ql[kc], s, 0, 0, 0);
        s = __builtin_amdgcn_mfma_f32_16x16x32_bf16(kl, qh[kc], s, 0, 0, 0);
        s = __builtin_amdgcn_mfma_f32_16x16x32_bf16(kh, qh[kc], s, 0, 0, 0);
      }
      sc[nb] = s;
    }
    __builtin_amdgcn_s_setprio(0);

    // in-lane row max over this lane's 16 keys, then across the 4 g-copies
    float m0 = fmaxf(fmaxf(sc[0][0], sc[0][1]), fmaxf(sc[0][2], sc[0][3]));
#pragma unroll
    for (int nb = 1; nb < 4; ++nb)
      m0 = fmaxf(m0, fmaxf(fmaxf(sc[nb][0], sc[nb][1]),
                           fmaxf(sc[nb][2], sc[nb][3])));
    m0 = fmaxf(m0, __shfl_xor(m0, 16));
    m0 = fmaxf(m0, __shfl_xor(m0, 32));

    if (__any(m0 > mrun + 8.0f)) {       // defer-max: p bounded by 2^8
      float mnew = fmaxf(mrun, m0);
      float scale = exp2f(mrun - mnew);
      mrun = mnew;
      lpart *= scale;
      // o rows are 4g+j -> fetch those rows' scales from lanes (g*16 + 4g+j)
      int sb = (g << 4) | (g << 2);
      float s0 = __shfl(scale, sb);
      float s1 = __shfl(scale, sb + 1);
      float s2 = __shfl(scale, sb + 2);
      float s3 = __shfl(scale, sb + 3);
#pragma unroll
      for (int db = 0; db < 4; ++db) {
        o[db][0] *= s0; o[db][1] *= s1; o[db][2] *= s2; o[db][3] *= s3;
      }
    }

    // p = exp2(sc - m) in-lane; accumulate partial sum; pack PV A-fragments
#pragma unroll
    for (int nb = 0; nb < 4; ++nb)
#pragma unroll
      for (int j = 0; j < 4; ++j)
        sc[nb][j] = exp2f(sc[nb][j] - mrun);
#pragma unroll
    for (int nb = 0; nb < 4; ++nb)
      lpart += (sc[nb][0] + sc[nb][1]) + (sc[nb][2] + sc[nb][3]);

    union { bf8 v; unsigned u[4]; } pa[2];
#pragma unroll
    for (int kc = 0; kc < 2; ++kc) {
      pa[kc].u[0] = (fbits(sc[2*kc][0]) >> 16)   | (fbits(sc[2*kc][1])   & 0xffff0000u);
      pa[kc].u[1] = (fbits(sc[2*kc][2]) >> 16)   | (fbits(sc[2*kc][3])   & 0xffff0000u);
      pa[kc].u[2] = (fbits(sc[2*kc+1][0]) >> 16) | (fbits(sc[2*kc+1][1]) & 0xffff0000u);
      pa[kc].u[3] = (fbits(sc[2*kc+1][2]) >> 16) | (fbits(sc[2*kc+1][3]) & 0xffff0000u);
    }

    // PV: A = packed P (key-permuted), B = V fragment (same permutation)
    __builtin_amdgcn_s_setprio(1);
#pragma unroll
    for (int kc = 0; kc < 2; ++kc)
#pragma unroll
      for (int db = 0; db < 4; ++db) {
        bf8 vb = *(const bf8*)&VV[koff[kc][db]];
        o[db] = __builtin_amdgcn_mfma_f32_16x16x32_bf16(pa[kc].v, vb, o[db], 0, 0, 0);
      }
    __builtin_amdgcn_s_setprio(0);

    __syncthreads();   // drains vmcnt (next tile staged) + cur reads done
  }

  // final: lsum for row c (sum the 4 g-copies), then fetch rows 4g+j
  lpart += __shfl_xor(lpart, 16);
  lpart += __shfl_xor(lpart, 32);
  int sb = (g << 4) | (g << 2);
  float r0 = 1.f / __shfl(lpart, sb);
  float r1 = 1.f / __shfl(lpart, sb + 1);
  float r2 = 1.f / __shfl(lpart, sb + 2);
  float r3 = 1.f / __shfl(lpart, sb + 3);

  const int b = bh >> 4, h = bh & 15;
#pragma unroll
  for (int db = 0; db < 4; ++db) {
    int col = h * DH + db * 16 + c;
    out[((size_t)b * S_LEN + q0 + g * 4 + 0) * DM + col] = o[db][0] * r0;
    out[((size_t)b * S_LEN + q0 + g * 4 + 1) * DM + col] = o[db][1] * r1;
    out[((size_t)b * S_LEN + q0 + g * 4 + 2) * DM + col] = o[db][2] * r2;
    out[((size_t)b * S_LEN + q0 + g * 4 + 3) * DM + col] = o[db][3] * r3;
  }
}

// ---------------------------------------------------------------------------
extern "C" void kernel_launch(void* const* d_in, const int* in_sizes, int n_in,
                              void* d_out, int out_size, void* d_ws, size_t ws_size,
                              hipStream_t stream) {
  const float* X    = (const float*)d_in[0];
  const float* W    = (const float*)d_in[1];
  const float* bias = (const float*)d_in[2];
  float* out = (float*)d_out;

  char* ws = (char*)d_ws;
  size_t off = 0;
  auto take = [&](size_t bytes) {
    void* p = ws + off;
    off += (bytes + 255) & ~(size_t)255;
    return p;
  };
  short* Xh  = (short*)take((size_t)NROWS * DM * 2);   // 8.4 MB
  short* Xl  = (short*)take((size_t)NROWS * DM * 2);
  short* Wth = (short*)take((size_t)EW * DM * 2);      // 6.3 MB
  short* Wtl = (short*)take((size_t)EW * DM * 2);
  short* Qh  = (short*)take((size_t)2 * NH * S_LEN * DH * 2);  // 8.4 MB each
  short* Ql  = (short*)take((size_t)2 * NH * S_LEN * DH * 2);
  short* Kh  = (short*)take((size_t)2 * NH * NT * 4096 * 2);
  short* Kl  = (short*)take((size_t)2 * NH * NT * 4096 * 2);
  short* Vt  = (short*)take((size_t)2 * NH * NT * 4096 * 2);
  // total ~71.3 MB of workspace

  prep_x<<<dim3(4096), dim3(256), 0, stream>>>(X, Xh, Xl);
  prep_w<<<dim3(EW / 32, DM / 32), dim3(256), 0, stream>>>(W, Wth, Wtl);
  proj<<<dim3(768), dim3(256), 0, stream>>>(
      Xh, Xl, Wth, Wtl, bias, Qh, Ql, Kh, Kl, Vt);
  attn<<<dim3(512), dim3(512), 0, stream>>>(
      Qh, Ql, Kh, Kl, Vt, out);
}

// Round 7
// 195.299 us; speedup vs baseline: 1.1569x; 1.0581x over previous
//
#include <hip/hip_runtime.h>

// ---------------------------------------------------------------------------
// SelfAttention: qkv = X@W + b ; per-head softmax(q k^T * sqrt(64)) @ v
// fp32 in/out. Precision (v5-proven, absmax 0.03125): split-bf16 3-pass MFMA
// for projection and Q*K^T, fp32 softmax (exp2 domain), bf16 PV.
// v7: proj upgraded to v6's pipeline (dbuf LDS, stage-next-before-compute,
// ONE barrier per K-step, XCD row-band grid) with all 4 matrices staged.
// attn = v5 verbatim (swapped QK^T, in-lane softmax, reg-packed P).
// ---------------------------------------------------------------------------

#define S_LEN 2048
#define NH    16
#define DH    64
#define DM    1024
#define EW    3072   // NH*(64+64+64)
#define NROWS 4096   // B*S
#define NT    32     // KV tiles of 64 keys

// 8 * log2(e): folds the sqrt(64) score scale AND the exp->exp2 conversion
#define QSCALE 11.5415603f

using f32x4 = __attribute__((ext_vector_type(4))) float;
using bf8   = __attribute__((ext_vector_type(8))) short;   // 8 bf16 (4 VGPRs)
using s4v   = __attribute__((ext_vector_type(4))) short;

static __device__ __forceinline__ short f2bf(float f) {
  union { float f; unsigned u; } a; a.f = f;
  unsigned r = a.u + 0x7fffu + ((a.u >> 16) & 1u);   // RNE
  return (short)(r >> 16);
}
static __device__ __forceinline__ float bf2f(short h) {
  union { float f; unsigned u; } a;
  a.u = ((unsigned)(unsigned short)h) << 16;
  return a.f;
}
static __device__ __forceinline__ unsigned fbits(float f) {
  union { float f; unsigned u; } a; a.f = f; return a.u;
}
static __device__ __forceinline__ void gl16(const void* g, void* l) {
  __builtin_amdgcn_global_load_lds(
      (const __attribute__((address_space(1))) void*)g,
      (__attribute__((address_space(3))) void*)l, 16, 0, 0);
}

// --------------------------- prep: split X into bf16 hi/lo ------------------
__global__ __launch_bounds__(256) void prep_x(const float* __restrict__ X,
                                              short* __restrict__ Xh,
                                              short* __restrict__ Xl) {
  int i = blockIdx.x * 256 + threadIdx.x;              // 1,048,576 float4s
  float4 v = ((const float4*)X)[i];
  s4v h, l;
  h.x = f2bf(v.x); l.x = f2bf(v.x - bf2f(h.x));
  h.y = f2bf(v.y); l.y = f2bf(v.y - bf2f(h.y));
  h.z = f2bf(v.z); l.z = f2bf(v.z - bf2f(h.z));
  h.w = f2bf(v.w); l.w = f2bf(v.w - bf2f(h.w));
  ((s4v*)Xh)[i] = h;
  ((s4v*)Xl)[i] = l;
}

// ------------------- prep: transpose W -> W^T, split hi/lo ------------------
__global__ __launch_bounds__(256) void prep_w(const float* __restrict__ W,
                                              short* __restrict__ Wth,
                                              short* __restrict__ Wtl) {
  __shared__ float t[32][33];
  int n0 = blockIdx.x * 32;
  int k0 = blockIdx.y * 32;
  int tx = threadIdx.x & 31;
  int ty = threadIdx.x >> 5;        // 0..7
#pragma unroll
  for (int i = 0; i < 32; i += 8)
    t[ty + i][tx] = W[(size_t)(k0 + ty + i) * EW + n0 + tx];
  __syncthreads();
#pragma unroll
  for (int i = 0; i < 32; i += 8) {
    float v = t[tx][ty + i];        // k = k0+tx, n = n0+ty+i
    short hi = f2bf(v);
    short lo = f2bf(v - bf2f(hi));
    size_t o = (size_t)(n0 + ty + i) * DM + k0 + tx;
    Wth[o] = hi; Wtl[o] = lo;
  }
}

// --------------------------- projection GEMM --------------------------------
// C(4096x3072) = X@W, split-bf16 3-pass. 128x128 tile, 4 waves, BK=32.
// 2-phase pipeline: double-buffered LDS (4 matrices, 64KB), stage(next) via
// global_load_lds before compute(cur), ONE barrier per K-step. Chunk-XOR
// swizzle (rule #21): pre-swizzled global source + same XOR on ds_read.
__global__ __launch_bounds__(256, 2) void proj(
    const short* __restrict__ Xh, const short* __restrict__ Xl,
    const short* __restrict__ Wth, const short* __restrict__ Wtl,
    const float* __restrict__ bias,
    short* __restrict__ Qh, short* __restrict__ Ql,
    short* __restrict__ Kh, short* __restrict__ Kl,
    short* __restrict__ Vt) {
  __shared__ short Ah[2][4096], Al[2][4096], Bh[2][4096], Bl[2][4096]; // 64KB
  const int tid = threadIdx.x;
  const int lane = tid & 63, w = tid >> 6;
  const int wr = w >> 1, wc = w & 1;
  const int c = lane & 15, g = lane >> 4;

  // XCD row-band grid: xcd = id&7 owns rows [xcd*4, xcd*4+4) x all 24 cols.
  const int id = blockIdx.x;                  // 0..767
  const int rowBase = (((id & 7) << 2) + ((id >> 3) & 3)) * 128;
  const int colBase = (id >> 5) * 128;

  f32x4 acc[4][4] = {};

  // staging: wave w stages rows [32w,32w+32), 2 segments of 16 rows; lane
  // covers one 16B chunk; global source chunk pre-swizzled by (row>>1)&3.
  const int sr  = 32 * w + (lane >> 2);
  const int csw = ((lane & 3) ^ ((lane >> 3) & 3)) * 8;   // shorts
  const int ldsw = w * 1024;                              // shorts, seg base
  const size_t aBase = (size_t)(rowBase + sr) * DM + csw;
  const size_t bBase = (size_t)(colBase + sr) * DM + csw;

  // read-side swizzle: row = (16-aligned) + c  ->  f(row) = (c>>1)&3
  const int rsw = (g ^ ((c >> 1) & 3)) * 8;

#define PSTAGE(B, kt) do {                                    \
    gl16(&Xh[aBase + (kt)],            &Ah[B][ldsw]);         \
    gl16(&Xh[aBase + (kt) + 16 * DM],  &Ah[B][ldsw + 512]);   \
    gl16(&Xl[aBase + (kt)],            &Al[B][ldsw]);         \
    gl16(&Xl[aBase + (kt) + 16 * DM],  &Al[B][ldsw + 512]);   \
    gl16(&Wth[bBase + (kt)],           &Bh[B][ldsw]);         \
    gl16(&Wth[bBase + (kt) + 16 * DM], &Bh[B][ldsw + 512]);   \
    gl16(&Wtl[bBase + (kt)],           &Bl[B][ldsw]);         \
    gl16(&Wtl[bBase + (kt) + 16 * DM], &Bl[B][ldsw + 512]);   \
  } while (0)

  PSTAGE(0, 0);
  __syncthreads();                       // vmcnt drained by compiler

  for (int it = 0; it < 32; ++it) {
    const int cur = it & 1;
    if (it + 1 < 32) PSTAGE(cur ^ 1, (it + 1) * 32);   // lands under MFMA

    bf8 ah[4], al4[4], bh[4], bl[4];
#pragma unroll
    for (int m = 0; m < 4; ++m) {
      int ro = (wr * 64 + m * 16 + c) * 32 + rsw;
      ah[m]  = *(const bf8*)&Ah[cur][ro];
      al4[m] = *(const bf8*)&Al[cur][ro];
    }
#pragma unroll
    for (int n = 0; n < 4; ++n) {
      int ro = (wc * 64 + n * 16 + c) * 32 + rsw;
      bh[n] = *(const bf8*)&Bh[cur][ro];
      bl[n] = *(const bf8*)&Bl[cur][ro];
    }
    __builtin_amdgcn_s_setprio(1);
#pragma unroll
    for (int m = 0; m < 4; ++m)
#pragma unroll
      for (int n = 0; n < 4; ++n) {
        acc[m][n] = __builtin_amdgcn_mfma_f32_16x16x32_bf16(al4[m], bh[n], acc[m][n], 0, 0, 0);
        acc[m][n] = __builtin_amdgcn_mfma_f32_16x16x32_bf16(ah[m], bl[n], acc[m][n], 0, 0, 0);
        acc[m][n] = __builtin_amdgcn_mfma_f32_16x16x32_bf16(ah[m], bh[n], acc[m][n], 0, 0, 0);
      }
    __builtin_amdgcn_s_setprio(0);
    __syncthreads();                     // reads done + staged tile visible
  }
#undef PSTAGE

  // epilogue: bias + scatter to per-head Q/K/V layouts
#pragma unroll
  for (int m = 0; m < 4; ++m)
#pragma unroll
    for (int n = 0; n < 4; ++n)
#pragma unroll
      for (int j = 0; j < 4; ++j) {
        int grow = rowBase + wr * 64 + m * 16 + g * 4 + j;   // 0..4095
        int gcol = colBase + wc * 64 + n * 16 + c;           // 0..3071
        float v = acc[m][n][j] + bias[gcol];
        int bb = grow >> 11, s = grow & 2047;
        int h = gcol / 192, e = gcol - h * 192;
        size_t hb = (size_t)(bb * NH + h);
        if (e < DH) {                      // Q: fold in 8*log2e (exp2 domain)
          float q8 = v * QSCALE;
          short hi = f2bf(q8);
          short lo = f2bf(q8 - bf2f(hi));
          size_t idx = (hb * S_LEN + s) * DH + e;
          Qh[idx] = hi; Ql[idx] = lo;
        } else if (e < 2 * DH) {
          // K: [bh][tile][key][d], chunk-XOR-swizzled: chunk ^= key&7
          short hi = f2bf(v);
          short lo = f2bf(v - bf2f(hi));
          int tile = s >> 6, r = s & 63, d = e - DH;
          size_t idx = ((hb * NT + tile) * (size_t)4096) + r * 64 +
                       ((((d >> 3) ^ (r & 7)) << 3) | (d & 7));
          Kh[idx] = hi; Kl[idx] = lo;
        } else {
          // V: [bh][tile][d][key-permuted], chunk-XOR-swizzled by d&7.
          // key -> slot: kc=key>>5, g4=(key>>2)&3, i=((key>>4)&1)*4+(key&3)
          int tile = s >> 6, key = s & 63, d = e - 2 * DH;
          int kc = key >> 5, g4 = (key >> 2) & 3;
          int ii = (((key >> 4) & 1) << 2) | (key & 3);
          size_t idx = ((hb * NT + tile) * (size_t)4096) + d * 64 +
                       (((((kc << 2) | g4) ^ (d & 7)) << 3) | ii);
          Vt[idx] = f2bf(v);
        }
      }
}

// ------------------------------ attention -----------------------------------
// 512 blocks (XCD-swizzled), 8 waves x 16 q-rows share one bh. Swapped QK^T:
// sc = mfma(K,Q) puts one q-row's scores in each lane -> in-lane softmax,
// P packed in registers straight into the PV A-fragment (V key-permuted).
// KV staged via global_load_lds, double-buffered, ONE barrier per tile.
__global__ __launch_bounds__(512, 4) void attn(
    const short* __restrict__ Qh, const short* __restrict__ Ql,
    const short* __restrict__ KhG, const short* __restrict__ KlG,
    const short* __restrict__ VtG, float* __restrict__ out) {
  __shared__ short KHs[2][4096];   // 16 KB
  __shared__ short KLs[2][4096];   // 16 KB
  __shared__ short Vs[2][4096];    // 16 KB

  const int tid = threadIdx.x;
  const int lane = tid & 63, w = tid >> 6;     // 8 waves
  const int c = lane & 15, g = lane >> 4;
  const int id = blockIdx.x;                   // 0..511
  const int lid = (id & 7) * 64 + (id >> 3);   // 64 consecutive per XCD
  const int bh = lid >> 4;
  const int q0 = (lid & 15) * 128 + w * 16;
  const size_t qBase  = (size_t)bh * S_LEN * DH;
  const size_t kvBase = (size_t)bh * NT * 4096;

  const int seg = tid * 8;     // one 16B chunk per thread per buffer

  // q fragments (hi/lo), rows q0+c — used as the MFMA B operand
  bf8 qh[2], ql[2];
#pragma unroll
  for (int kc = 0; kc < 2; ++kc) {
    size_t idx = qBase + (size_t)(q0 + c) * DH + kc * 32 + g * 8;
    qh[kc] = *(const bf8*)&Qh[idx];
    ql[kc] = *(const bf8*)&Ql[idx];
  }

  // t-invariant swizzled fragment offsets ((i*16+c)&7 == c&7)
  int koff[2][4];
#pragma unroll
  for (int kc = 0; kc < 2; ++kc)
#pragma unroll
    for (int i = 0; i < 4; ++i)
      koff[kc][i] = (i * 16 + c) * 64 + (((kc * 4 + g) ^ (c & 7)) << 3);

  float mrun = -INFINITY, lpart = 0.f;   // state for q-row c (dup across g)
  f32x4 o[4] = {};                       // o[db][j]: row 4g+j, d = db*16+c

  // prologue: stage tile 0
  gl16(&KhG[kvBase + seg], &KHs[0][seg]);
  gl16(&KlG[kvBase + seg], &KLs[0][seg]);
  gl16(&VtG[kvBase + seg], &Vs[0][seg]);
  __syncthreads();

  for (int t = 0; t < NT; ++t) {
    const int cur = t & 1, nxt = cur ^ 1;
    if (t + 1 < NT) {                    // DMA next tile; lands under compute
      size_t tb = kvBase + (size_t)(t + 1) * 4096 + seg;
      gl16(&KhG[tb], &KHs[nxt][seg]);
      gl16(&KlG[tb], &KLs[nxt][seg]);
      gl16(&VtG[tb], &Vs[nxt][seg]);
    }
    const short* KH = &KHs[cur][0];
    const short* KL = &KLs[cur][0];
    const short* VV = &Vs[cur][0];

    // scores, swapped: sc[nb][j] = S[key=16nb+4g+j][q-row c]
    f32x4 sc[4];
    __builtin_amdgcn_s_setprio(1);
#pragma unroll
    for (int nb = 0; nb < 4; ++nb) {
      f32x4 s = {};
#pragma unroll
      for (int kc = 0; kc < 2; ++kc) {
        bf8 kh = *(const bf8*)&KH[koff[kc][nb]];
        bf8 kl = *(const bf8*)&KL[koff[kc][nb]];
        s = __builtin_amdgcn_mfma_f32_16x16x32_bf16(kh, ql[kc], s, 0, 0, 0);
        s = __builtin_amdgcn_mfma_f32_16x16x32_bf16(kl, qh[kc], s, 0, 0, 0);
        s = __builtin_amdgcn_mfma_f32_16x16x32_bf16(kh, qh[kc], s, 0, 0, 0);
      }
      sc[nb] = s;
    }
    __builtin_amdgcn_s_setprio(0);

    // in-lane row max over this lane's 16 keys, then across the 4 g-copies
    float m0 = fmaxf(fmaxf(sc[0][0], sc[0][1]), fmaxf(sc[0][2], sc[0][3]));
#pragma unroll
    for (int nb = 1; nb < 4; ++nb)
      m0 = fmaxf(m0, fmaxf(fmaxf(sc[nb][0], sc[nb][1]),
                           fmaxf(sc[nb][2], sc[nb][3])));
    m0 = fmaxf(m0, __shfl_xor(m0, 16));
    m0 = fmaxf(m0, __shfl_xor(m0, 32));

    if (__any(m0 > mrun + 8.0f)) {       // defer-max: p bounded by 2^8
      float mnew = fmaxf(mrun, m0);
      float scale = exp2f(mrun - mnew);
      mrun = mnew;
      lpart *= scale;
      int sb = (g << 4) | (g << 2);
      float s0 = __shfl(scale, sb);
      float s1 = __shfl(scale, sb + 1);
      float s2 = __shfl(scale, sb + 2);
      float s3 = __shfl(scale, sb + 3);
#pragma unroll
      for (int db = 0; db < 4; ++db) {
        o[db][0] *= s0; o[db][1] *= s1; o[db][2] *= s2; o[db][3] *= s3;
      }
    }

    // p = exp2(sc - m) in-lane; partial sum; pack bf16 PV A-fragments
#pragma unroll
    for (int nb = 0; nb < 4; ++nb)
#pragma unroll
      for (int j = 0; j < 4; ++j)
        sc[nb][j] = exp2f(sc[nb][j] - mrun);
#pragma unroll
    for (int nb = 0; nb < 4; ++nb)
      lpart += (sc[nb][0] + sc[nb][1]) + (sc[nb][2] + sc[nb][3]);

    union { bf8 v; unsigned u[4]; } pa[2];
#pragma unroll
    for (int kc = 0; kc < 2; ++kc) {
      pa[kc].u[0] = (fbits(sc[2*kc][0]) >> 16)   | (fbits(sc[2*kc][1])   & 0xffff0000u);
      pa[kc].u[1] = (fbits(sc[2*kc][2]) >> 16)   | (fbits(sc[2*kc][3])   & 0xffff0000u);
      pa[kc].u[2] = (fbits(sc[2*kc+1][0]) >> 16) | (fbits(sc[2*kc+1][1]) & 0xffff0000u);
      pa[kc].u[3] = (fbits(sc[2*kc+1][2]) >> 16) | (fbits(sc[2*kc+1][3]) & 0xffff0000u);
    }

    // PV: A = packed P (key-permuted), B = V fragment (same permutation)
    __builtin_amdgcn_s_setprio(1);
#pragma unroll
    for (int kc = 0; kc < 2; ++kc)
#pragma unroll
      for (int db = 0; db < 4; ++db) {
        bf8 vb = *(const bf8*)&VV[koff[kc][db]];
        o[db] = __builtin_amdgcn_mfma_f32_16x16x32_bf16(pa[kc].v, vb, o[db], 0, 0, 0);
      }
    __builtin_amdgcn_s_setprio(0);

    __syncthreads();   // drains vmcnt (next tile staged) + cur reads done
  }

  // final: lsum for row c (sum the 4 g-copies), then fetch rows 4g+j
  lpart += __shfl_xor(lpart, 16);
  lpart += __shfl_xor(lpart, 32);
  int sb = (g << 4) | (g << 2);
  float r0 = 1.f / __shfl(lpart, sb);
  float r1 = 1.f / __shfl(lpart, sb + 1);
  float r2 = 1.f / __shfl(lpart, sb + 2);
  float r3 = 1.f / __shfl(lpart, sb + 3);

  const int b = bh >> 4, h = bh & 15;
#pragma unroll
  for (int db = 0; db < 4; ++db) {
    int col = h * DH + db * 16 + c;
    out[((size_t)b * S_LEN + q0 + g * 4 + 0) * DM + col] = o[db][0] * r0;
    out[((size_t)b * S_LEN + q0 + g * 4 + 1) * DM + col] = o[db][1] * r1;
    out[((size_t)b * S_LEN + q0 + g * 4 + 2) * DM + col] = o[db][2] * r2;
    out[((size_t)b * S_LEN + q0 + g * 4 + 3) * DM + col] = o[db][3] * r3;
  }
}

// ---------------------------------------------------------------------------
extern "C" void kernel_launch(void* const* d_in, const int* in_sizes, int n_in,
                              void* d_out, int out_size, void* d_ws, size_t ws_size,
                              hipStream_t stream) {
  const float* X    = (const float*)d_in[0];
  const float* W    = (const float*)d_in[1];
  const float* bias = (const float*)d_in[2];
  float* out = (float*)d_out;

  char* ws = (char*)d_ws;
  size_t off = 0;
  auto take = [&](size_t bytes) {
    void* p = ws + off;
    off += (bytes + 255) & ~(size_t)255;
    return p;
  };
  short* Xh  = (short*)take((size_t)NROWS * DM * 2);   // 8.4 MB
  short* Xl  = (short*)take((size_t)NROWS * DM * 2);
  short* Wth = (short*)take((size_t)EW * DM * 2);      // 6.3 MB
  short* Wtl = (short*)take((size_t)EW * DM * 2);
  short* Qh  = (short*)take((size_t)2 * NH * S_LEN * DH * 2);  // 8.4 MB each
  short* Ql  = (short*)take((size_t)2 * NH * S_LEN * DH * 2);
  short* Kh  = (short*)take((size_t)2 * NH * NT * 4096 * 2);
  short* Kl  = (short*)take((size_t)2 * NH * NT * 4096 * 2);
  short* Vt  = (short*)take((size_t)2 * NH * NT * 4096 * 2);
  // total ~71.3 MB of workspace

  prep_x<<<dim3(4096), dim3(256), 0, stream>>>(X, Xh, Xl);
  prep_w<<<dim3(EW / 32, DM / 32), dim3(256), 0, stream>>>(W, Wth, Wtl);
  proj<<<dim3(768), dim3(256), 0, stream>>>(
      Xh, Xl, Wth, Wtl, bias, Qh, Ql, Kh, Kl, Vt);
  attn<<<dim3(512), dim3(512), 0, stream>>>(
      Qh, Ql, Kh, Kl, Vt, out);
}

// Round 8
// 174.546 us; speedup vs baseline: 1.2945x; 1.1189x over previous
//
#include <hip/hip_runtime.h>

// ---------------------------------------------------------------------------
// SelfAttention: qkv = X@W + b ; per-head softmax(q k^T * sqrt(64)) @ v
// fp32 in/out. Precision: split-bf16 3-pass MFMA for QK projection and
// Q*K^T (logit sigma ~3e-4), 1-pass bf16 for V projection (V sigma ~3e-3,
// never touches softmax), fp32 softmax (exp2 domain), bf16 PV.
// v8: W columns permuted to [Q|K|V]; proj split into proj_qk (3-pass) and
// proj_v (1-pass, half staging); frag-reads issued before stage-of-next.
// attn = v5 verbatim (swapped QK^T, in-lane softmax, reg-packed P).
// ---------------------------------------------------------------------------

#define S_LEN 2048
#define NH    16
#define DH    64
#define DM    1024
#define EW    3072   // NH*(64+64+64)
#define NROWS 4096   // B*S
#define NT    32     // KV tiles of 64 keys

// 8 * log2(e): folds the sqrt(64) score scale AND the exp->exp2 conversion
#define QSCALE 11.5415603f

using f32x4 = __attribute__((ext_vector_type(4))) float;
using bf8   = __attribute__((ext_vector_type(8))) short;   // 8 bf16 (4 VGPRs)
using s4v   = __attribute__((ext_vector_type(4))) short;

static __device__ __forceinline__ short f2bf(float f) {
  union { float f; unsigned u; } a; a.f = f;
  unsigned r = a.u + 0x7fffu + ((a.u >> 16) & 1u);   // RNE
  return (short)(r >> 16);
}
static __device__ __forceinline__ float bf2f(short h) {
  union { float f; unsigned u; } a;
  a.u = ((unsigned)(unsigned short)h) << 16;
  return a.f;
}
static __device__ __forceinline__ unsigned fbits(float f) {
  union { float f; unsigned u; } a; a.f = f; return a.u;
}
static __device__ __forceinline__ void gl16(const void* g, void* l) {
  __builtin_amdgcn_global_load_lds(
      (const __attribute__((address_space(1))) void*)g,
      (__attribute__((address_space(3))) void*)l, 16, 0, 0);
}

// --------------------------- prep: split X into bf16 hi/lo ------------------
__global__ __launch_bounds__(256) void prep_x(const float* __restrict__ X,
                                              short* __restrict__ Xh,
                                              short* __restrict__ Xl) {
  int i = blockIdx.x * 256 + threadIdx.x;              // 1,048,576 float4s
  float4 v = ((const float4*)X)[i];
  s4v h, l;
  h.x = f2bf(v.x); l.x = f2bf(v.x - bf2f(h.x));
  h.y = f2bf(v.y); l.y = f2bf(v.y - bf2f(h.y));
  h.z = f2bf(v.z); l.z = f2bf(v.z - bf2f(h.z));
  h.w = f2bf(v.w); l.w = f2bf(v.w - bf2f(h.w));
  ((s4v*)Xh)[i] = h;
  ((s4v*)Xl)[i] = l;
}

// --------- prep: transpose W -> W^T, split hi/lo, permute cols [Q|K|V] ------
__global__ __launch_bounds__(256) void prep_w(const float* __restrict__ W,
                                              short* __restrict__ Wth,
                                              short* __restrict__ Wtl) {
  __shared__ float t[32][33];
  int n0 = blockIdx.x * 32;
  int k0 = blockIdx.y * 32;
  int tx = threadIdx.x & 31;
  int ty = threadIdx.x >> 5;        // 0..7
#pragma unroll
  for (int i = 0; i < 32; i += 8)
    t[ty + i][tx] = W[(size_t)(k0 + ty + i) * EW + n0 + tx];
  __syncthreads();
#pragma unroll
  for (int i = 0; i < 32; i += 8) {
    float v = t[tx][ty + i];        // k = k0+tx, n = n0+ty+i (original col)
    int n = n0 + ty + i;
    int h = n / 192, e = n - h * 192;
    int np = (e < 64) ? (h * 64 + e)
           : (e < 128) ? (1024 + h * 64 + (e - 64))
                       : (2048 + h * 64 + (e - 128));
    short hi = f2bf(v);
    short lo = f2bf(v - bf2f(hi));
    size_t o = (size_t)np * DM + k0 + tx;
    Wth[o] = hi; Wtl[o] = lo;
  }
}

// ------------------------- projection GEMM (Q,K cols) -----------------------
// C(4096x2048) = X@W[:, 0:2048], split-bf16 3-pass. 128x128 tile, 4 waves,
// BK=32, 2-phase pipeline (dbuf LDS 64KB, stage-next after frag-reads,
// ONE barrier per K-step). Chunk-XOR swizzle (rule #21).
__global__ __launch_bounds__(256, 2) void proj_qk(
    const short* __restrict__ Xh, const short* __restrict__ Xl,
    const short* __restrict__ Wth, const short* __restrict__ Wtl,
    const float* __restrict__ bias,
    short* __restrict__ Qh, short* __restrict__ Ql,
    short* __restrict__ Kh, short* __restrict__ Kl) {
  __shared__ short Ah[2][4096], Al[2][4096], Bh[2][4096], Bl[2][4096]; // 64KB
  const int tid = threadIdx.x;
  const int lane = tid & 63, w = tid >> 6;
  const int wr = w >> 1, wc = w & 1;
  const int c = lane & 15, g = lane >> 4;

  // XCD row-band grid: xcd = id&7 owns rows [xcd*4, xcd*4+4) x 16 col-strips
  const int id = blockIdx.x;                  // 0..511
  const int t = id >> 3;                      // 0..63
  const int rowBase = (((id & 7) << 2) + (t & 3)) * 128;
  const int colBase = (t >> 2) * 128;         // 0..1920

  f32x4 acc[4][4] = {};

  const int sr  = 32 * w + (lane >> 2);
  const int csw = ((lane & 3) ^ ((lane >> 3) & 3)) * 8;   // shorts
  const int ldsw = w * 1024;                              // shorts, seg base
  const size_t aBase = (size_t)(rowBase + sr) * DM + csw;
  const size_t bBase = (size_t)(colBase + sr) * DM + csw;

  // read-side swizzle: row = (16-aligned) + c  ->  f(row) = (c>>1)&3
  const int rsw = (g ^ ((c >> 1) & 3)) * 8;

#define PSTAGE(B, kt) do {                                    \
    gl16(&Xh[aBase + (kt)],            &Ah[B][ldsw]);         \
    gl16(&Xh[aBase + (kt) + 16 * DM],  &Ah[B][ldsw + 512]);   \
    gl16(&Xl[aBase + (kt)],            &Al[B][ldsw]);         \
    gl16(&Xl[aBase + (kt) + 16 * DM],  &Al[B][ldsw + 512]);   \
    gl16(&Wth[bBase + (kt)],           &Bh[B][ldsw]);         \
    gl16(&Wth[bBase + (kt) + 16 * DM], &Bh[B][ldsw + 512]);   \
    gl16(&Wtl[bBase + (kt)],           &Bl[B][ldsw]);         \
    gl16(&Wtl[bBase + (kt) + 16 * DM], &Bl[B][ldsw + 512]);   \
  } while (0)

  PSTAGE(0, 0);
  __syncthreads();                       // vmcnt drained by compiler

  for (int it = 0; it < 32; ++it) {
    const int cur = it & 1;

    bf8 ah[4], al4[4], bh[4], bl[4];
#pragma unroll
    for (int m = 0; m < 4; ++m) {
      int ro = (wr * 64 + m * 16 + c) * 32 + rsw;
      ah[m]  = *(const bf8*)&Ah[cur][ro];
      al4[m] = *(const bf8*)&Al[cur][ro];
    }
#pragma unroll
    for (int n = 0; n < 4; ++n) {
      int ro = (wc * 64 + n * 16 + c) * 32 + rsw;
      bh[n] = *(const bf8*)&Bh[cur][ro];
      bl[n] = *(const bf8*)&Bl[cur][ro];
    }
    if (it + 1 < 32) PSTAGE(cur ^ 1, (it + 1) * 32);   // lands under MFMA

    __builtin_amdgcn_s_setprio(1);
#pragma unroll
    for (int m = 0; m < 4; ++m)
#pragma unroll
      for (int n = 0; n < 4; ++n) {
        acc[m][n] = __builtin_amdgcn_mfma_f32_16x16x32_bf16(al4[m], bh[n], acc[m][n], 0, 0, 0);
        acc[m][n] = __builtin_amdgcn_mfma_f32_16x16x32_bf16(ah[m], bl[n], acc[m][n], 0, 0, 0);
        acc[m][n] = __builtin_amdgcn_mfma_f32_16x16x32_bf16(ah[m], bh[n], acc[m][n], 0, 0, 0);
      }
    __builtin_amdgcn_s_setprio(0);
    __syncthreads();                     // reads done + staged tile visible
  }
#undef PSTAGE

  // epilogue: bias + scatter to Q (hi/lo, exp2-scaled) or K (swizzled tiles)
#pragma unroll
  for (int m = 0; m < 4; ++m)
#pragma unroll
    for (int n = 0; n < 4; ++n)
#pragma unroll
      for (int j = 0; j < 4; ++j) {
        int grow = rowBase + wr * 64 + m * 16 + g * 4 + j;   // 0..4095
        int gcol = colBase + wc * 64 + n * 16 + c;           // 0..2047 (perm)
        int h = (gcol >> 6) & 15, e = gcol & 63;
        int bb = grow >> 11, s = grow & 2047;
        size_t hb = (size_t)(bb * NH + h);
        if (gcol < 1024) {                 // Q: orig col h*192+e
          float q8 = (acc[m][n][j] + bias[h * 192 + e]) * QSCALE;
          short hi = f2bf(q8);
          short lo = f2bf(q8 - bf2f(hi));
          size_t idx = (hb * S_LEN + s) * DH + e;
          Qh[idx] = hi; Ql[idx] = lo;
        } else {                           // K: orig col h*192+64+e
          float v = acc[m][n][j] + bias[h * 192 + 64 + e];
          short hi = f2bf(v);
          short lo = f2bf(v - bf2f(hi));
          int tile = s >> 6, r = s & 63;
          size_t idx = ((hb * NT + tile) * (size_t)4096) + r * 64 +
                       ((((e >> 3) ^ (r & 7)) << 3) | (e & 7));
          Kh[idx] = hi; Kl[idx] = lo;
        }
      }
}

// -------------------------- projection GEMM (V cols) ------------------------
// C(4096x1024) = X@W[:, 2048:3072], 1-pass bf16 (V never enters softmax;
// error sigma ~3e-3 << 0.109 budget). Stages only Ah+Bh (32KB LDS).
__global__ __launch_bounds__(256, 2) void proj_v(
    const short* __restrict__ Xh, const short* __restrict__ Wth,
    const float* __restrict__ bias, short* __restrict__ Vt) {
  __shared__ short Ah[2][4096], Bh[2][4096];   // 32KB
  const int tid = threadIdx.x;
  const int lane = tid & 63, w = tid >> 6;
  const int wr = w >> 1, wc = w & 1;
  const int c = lane & 15, g = lane >> 4;

  const int id = blockIdx.x;                  // 0..255
  const int t = id >> 3;                      // 0..31
  const int rowBase = (((id & 7) << 2) + (t & 3)) * 128;
  const int colBase = 2048 + (t >> 2) * 128;  // permuted V region

  f32x4 acc[4][4] = {};

  const int sr  = 32 * w + (lane >> 2);
  const int csw = ((lane & 3) ^ ((lane >> 3) & 3)) * 8;
  const int ldsw = w * 1024;
  const size_t aBase = (size_t)(rowBase + sr) * DM + csw;
  const size_t bBase = (size_t)(colBase + sr) * DM + csw;
  const int rsw = (g ^ ((c >> 1) & 3)) * 8;

#define VSTAGE(B, kt) do {                                    \
    gl16(&Xh[aBase + (kt)],            &Ah[B][ldsw]);         \
    gl16(&Xh[aBase + (kt) + 16 * DM],  &Ah[B][ldsw + 512]);   \
    gl16(&Wth[bBase + (kt)],           &Bh[B][ldsw]);         \
    gl16(&Wth[bBase + (kt) + 16 * DM], &Bh[B][ldsw + 512]);   \
  } while (0)

  VSTAGE(0, 0);
  __syncthreads();

  for (int it = 0; it < 32; ++it) {
    const int cur = it & 1;
    bf8 ah[4], bh[4];
#pragma unroll
    for (int m = 0; m < 4; ++m)
      ah[m] = *(const bf8*)&Ah[cur][(wr * 64 + m * 16 + c) * 32 + rsw];
#pragma unroll
    for (int n = 0; n < 4; ++n)
      bh[n] = *(const bf8*)&Bh[cur][(wc * 64 + n * 16 + c) * 32 + rsw];
    if (it + 1 < 32) VSTAGE(cur ^ 1, (it + 1) * 32);

    __builtin_amdgcn_s_setprio(1);
#pragma unroll
    for (int m = 0; m < 4; ++m)
#pragma unroll
      for (int n = 0; n < 4; ++n)
        acc[m][n] = __builtin_amdgcn_mfma_f32_16x16x32_bf16(ah[m], bh[n], acc[m][n], 0, 0, 0);
    __builtin_amdgcn_s_setprio(0);
    __syncthreads();
  }
#undef VSTAGE

  // epilogue: V -> [bh][tile][d][key-permuted], chunk-XOR-swizzled by d&7
#pragma unroll
  for (int m = 0; m < 4; ++m)
#pragma unroll
    for (int n = 0; n < 4; ++n)
#pragma unroll
      for (int j = 0; j < 4; ++j) {
        int grow = rowBase + wr * 64 + m * 16 + g * 4 + j;
        int gcol = colBase + wc * 64 + n * 16 + c;        // 2048..3071 (perm)
        int h = (gcol >> 6) & 15, d = gcol & 63;
        int bb = grow >> 11, s = grow & 2047;
        size_t hb = (size_t)(bb * NH + h);
        float v = acc[m][n][j] + bias[h * 192 + 128 + d];
        int tile = s >> 6, key = s & 63;
        int kc = key >> 5, g4 = (key >> 2) & 3;
        int ii = (((key >> 4) & 1) << 2) | (key & 3);
        size_t idx = ((hb * NT + tile) * (size_t)4096) + d * 64 +
                     (((((kc << 2) | g4) ^ (d & 7)) << 3) | ii);
        Vt[idx] = f2bf(v);
      }
}

// ------------------------------ attention -----------------------------------
// 512 blocks (XCD-swizzled), 8 waves x 16 q-rows share one bh. Swapped QK^T:
// sc = mfma(K,Q) puts one q-row's scores in each lane -> in-lane softmax,
// P packed in registers straight into the PV A-fragment (V key-permuted).
// KV staged via global_load_lds, double-buffered, ONE barrier per tile.
__global__ __launch_bounds__(512, 4) void attn(
    const short* __restrict__ Qh, const short* __restrict__ Ql,
    const short* __restrict__ KhG, const short* __restrict__ KlG,
    const short* __restrict__ VtG, float* __restrict__ out) {
  __shared__ short KHs[2][4096];   // 16 KB
  __shared__ short KLs[2][4096];   // 16 KB
  __shared__ short Vs[2][4096];    // 16 KB

  const int tid = threadIdx.x;
  const int lane = tid & 63, w = tid >> 6;     // 8 waves
  const int c = lane & 15, g = lane >> 4;
  const int id = blockIdx.x;                   // 0..511
  const int lid = (id & 7) * 64 + (id >> 3);   // 64 consecutive per XCD
  const int bh = lid >> 4;
  const int q0 = (lid & 15) * 128 + w * 16;
  const size_t qBase  = (size_t)bh * S_LEN * DH;
  const size_t kvBase = (size_t)bh * NT * 4096;

  const int seg = tid * 8;     // one 16B chunk per thread per buffer

  // q fragments (hi/lo), rows q0+c — used as the MFMA B operand
  bf8 qh[2], ql[2];
#pragma unroll
  for (int kc = 0; kc < 2; ++kc) {
    size_t idx = qBase + (size_t)(q0 + c) * DH + kc * 32 + g * 8;
    qh[kc] = *(const bf8*)&Qh[idx];
    ql[kc] = *(const bf8*)&Ql[idx];
  }

  // t-invariant swizzled fragment offsets ((i*16+c)&7 == c&7)
  int koff[2][4];
#pragma unroll
  for (int kc = 0; kc < 2; ++kc)
#pragma unroll
    for (int i = 0; i < 4; ++i)
      koff[kc][i] = (i * 16 + c) * 64 + (((kc * 4 + g) ^ (c & 7)) << 3);

  float mrun = -INFINITY, lpart = 0.f;   // state for q-row c (dup across g)
  f32x4 o[4] = {};                       // o[db][j]: row 4g+j, d = db*16+c

  // prologue: stage tile 0
  gl16(&KhG[kvBase + seg], &KHs[0][seg]);
  gl16(&KlG[kvBase + seg], &KLs[0][seg]);
  gl16(&VtG[kvBase + seg], &Vs[0][seg]);
  __syncthreads();

  for (int t = 0; t < NT; ++t) {
    const int cur = t & 1, nxt = cur ^ 1;
    if (t + 1 < NT) {                    // DMA next tile; lands under compute
      size_t tb = kvBase + (size_t)(t + 1) * 4096 + seg;
      gl16(&KhG[tb], &KHs[nxt][seg]);
      gl16(&KlG[tb], &KLs[nxt][seg]);
      gl16(&VtG[tb], &Vs[nxt][seg]);
    }
    const short* KH = &KHs[cur][0];
    const short* KL = &KLs[cur][0];
    const short* VV = &Vs[cur][0];

    // scores, swapped: sc[nb][j] = S[key=16nb+4g+j][q-row c]
    f32x4 sc[4];
    __builtin_amdgcn_s_setprio(1);
#pragma unroll
    for (int nb = 0; nb < 4; ++nb) {
      f32x4 s = {};
#pragma unroll
      for (int kc = 0; kc < 2; ++kc) {
        bf8 kh = *(const bf8*)&KH[koff[kc][nb]];
        bf8 kl = *(const bf8*)&KL[koff[kc][nb]];
        s = __builtin_amdgcn_mfma_f32_16x16x32_bf16(kh, ql[kc], s, 0, 0, 0);
        s = __builtin_amdgcn_mfma_f32_16x16x32_bf16(kl, qh[kc], s, 0, 0, 0);
        s = __builtin_amdgcn_mfma_f32_16x16x32_bf16(kh, qh[kc], s, 0, 0, 0);
      }
      sc[nb] = s;
    }
    __builtin_amdgcn_s_setprio(0);

    // in-lane row max over this lane's 16 keys, then across the 4 g-copies
    float m0 = fmaxf(fmaxf(sc[0][0], sc[0][1]), fmaxf(sc[0][2], sc[0][3]));
#pragma unroll
    for (int nb = 1; nb < 4; ++nb)
      m0 = fmaxf(m0, fmaxf(fmaxf(sc[nb][0], sc[nb][1]),
                           fmaxf(sc[nb][2], sc[nb][3])));
    m0 = fmaxf(m0, __shfl_xor(m0, 16));
    m0 = fmaxf(m0, __shfl_xor(m0, 32));

    if (__any(m0 > mrun + 8.0f)) {       // defer-max: p bounded by 2^8
      float mnew = fmaxf(mrun, m0);
      float scale = exp2f(mrun - mnew);
      mrun = mnew;
      lpart *= scale;
      int sb = (g << 4) | (g << 2);
      float s0 = __shfl(scale, sb);
      float s1 = __shfl(scale, sb + 1);
      float s2 = __shfl(scale, sb + 2);
      float s3 = __shfl(scale, sb + 3);
#pragma unroll
      for (int db = 0; db < 4; ++db) {
        o[db][0] *= s0; o[db][1] *= s1; o[db][2] *= s2; o[db][3] *= s3;
      }
    }

    // p = exp2(sc - m) in-lane; partial sum; pack bf16 PV A-fragments
#pragma unroll
    for (int nb = 0; nb < 4; ++nb)
#pragma unroll
      for (int j = 0; j < 4; ++j)
        sc[nb][j] = exp2f(sc[nb][j] - mrun);
#pragma unroll
    for (int nb = 0; nb < 4; ++nb)
      lpart += (sc[nb][0] + sc[nb][1]) + (sc[nb][2] + sc[nb][3]);

    union { bf8 v; unsigned u[4]; } pa[2];
#pragma unroll
    for (int kc = 0; kc < 2; ++kc) {
      pa[kc].u[0] = (fbits(sc[2*kc][0]) >> 16)   | (fbits(sc[2*kc][1])   & 0xffff0000u);
      pa[kc].u[1] = (fbits(sc[2*kc][2]) >> 16)   | (fbits(sc[2*kc][3])   & 0xffff0000u);
      pa[kc].u[2] = (fbits(sc[2*kc+1][0]) >> 16) | (fbits(sc[2*kc+1][1]) & 0xffff0000u);
      pa[kc].u[3] = (fbits(sc[2*kc+1][2]) >> 16) | (fbits(sc[2*kc+1][3]) & 0xffff0000u);
    }

    // PV: A = packed P (key-permuted), B = V fragment (same permutation)
    __builtin_amdgcn_s_setprio(1);
#pragma unroll
    for (int kc = 0; kc < 2; ++kc)
#pragma unroll
      for (int db = 0; db < 4; ++db) {
        bf8 vb = *(const bf8*)&VV[koff[kc][db]];
        o[db] = __builtin_amdgcn_mfma_f32_16x16x32_bf16(pa[kc].v, vb, o[db], 0, 0, 0);
      }
    __builtin_amdgcn_s_setprio(0);

    __syncthreads();   // drains vmcnt (next tile staged) + cur reads done
  }

  // final: lsum for row c (sum the 4 g-copies), then fetch rows 4g+j
  lpart += __shfl_xor(lpart, 16);
  lpart += __shfl_xor(lpart, 32);
  int sb = (g << 4) | (g << 2);
  float r0 = 1.f / __shfl(lpart, sb);
  float r1 = 1.f / __shfl(lpart, sb + 1);
  float r2 = 1.f / __shfl(lpart, sb + 2);
  float r3 = 1.f / __shfl(lpart, sb + 3);

  const int b = bh >> 4, h = bh & 15;
#pragma unroll
  for (int db = 0; db < 4; ++db) {
    int col = h * DH + db * 16 + c;
    out[((size_t)b * S_LEN + q0 + g * 4 + 0) * DM + col] = o[db][0] * r0;
    out[((size_t)b * S_LEN + q0 + g * 4 + 1) * DM + col] = o[db][1] * r1;
    out[((size_t)b * S_LEN + q0 + g * 4 + 2) * DM + col] = o[db][2] * r2;
    out[((size_t)b * S_LEN + q0 + g * 4 + 3) * DM + col] = o[db][3] * r3;
  }
}

// ---------------------------------------------------------------------------
extern "C" void kernel_launch(void* const* d_in, const int* in_sizes, int n_in,
                              void* d_out, int out_size, void* d_ws, size_t ws_size,
                              hipStream_t stream) {
  const float* X    = (const float*)d_in[0];
  const float* W    = (const float*)d_in[1];
  const float* bias = (const float*)d_in[2];
  float* out = (float*)d_out;

  char* ws = (char*)d_ws;
  size_t off = 0;
  auto take = [&](size_t bytes) {
    void* p = ws + off;
    off += (bytes + 255) & ~(size_t)255;
    return p;
  };
  short* Xh  = (short*)take((size_t)NROWS * DM * 2);   // 8.4 MB
  short* Xl  = (short*)take((size_t)NROWS * DM * 2);
  short* Wth = (short*)take((size_t)EW * DM * 2);      // 6.3 MB
  short* Wtl = (short*)take((size_t)EW * DM * 2);
  short* Qh  = (short*)take((size_t)2 * NH * S_LEN * DH * 2);  // 8.4 MB each
  short* Ql  = (short*)take((size_t)2 * NH * S_LEN * DH * 2);
  short* Kh  = (short*)take((size_t)2 * NH * NT * 4096 * 2);
  short* Kl  = (short*)take((size_t)2 * NH * NT * 4096 * 2);
  short* Vt  = (short*)take((size_t)2 * NH * NT * 4096 * 2);
  // total ~71.3 MB of workspace

  prep_x<<<dim3(4096), dim3(256), 0, stream>>>(X, Xh, Xl);
  prep_w<<<dim3(EW / 32, DM / 32), dim3(256), 0, stream>>>(W, Wth, Wtl);
  proj_qk<<<dim3(512), dim3(256), 0, stream>>>(
      Xh, Xl, Wth, Wtl, bias, Qh, Ql, Kh, Kl);
  proj_v<<<dim3(256), dim3(256), 0, stream>>>(Xh, Wth, bias, Vt);
  attn<<<dim3(512), dim3(512), 0, stream>>>(
      Qh, Ql, Kh, Kl, Vt, out);
}